// Round 1
// baseline (108.914 us; speedup 1.0000x reference)
//
#include <hip/hip_runtime.h>
#include <hip/hip_bf16.h>
#include <stdint.h>

// Problem constants (from reference setup_inputs)
constexpr int cB  = 8;
constexpr int cC  = 256;
constexpr int cHW = 128 * 128;   // 16384
constexpr int cN  = 100;
constexpr int cT  = 6;
constexpr int NPAD = 112;        // cN padded to multiple of 16
constexpr int KC  = 512;         // pixels per workgroup chunk
constexpr int KS  = 128;         // pixels per LDS subtile
constexpr int NSUB = KC / KS;    // 4
constexpr int KCHUNKS = cHW / KC; // 32

typedef __attribute__((ext_vector_type(8))) short short8;
typedef __attribute__((ext_vector_type(4))) float floatx4;

__device__ __forceinline__ unsigned short f2bf(float f) {
    union { float f; unsigned u; } v; v.f = f;
    unsigned u = v.u;
    unsigned r = u + 0x7fffu + ((u >> 16) & 1u);   // RNE (inputs are normal floats)
    return (unsigned short)(r >> 16);
}

// ---------------------------------------------------------------------------
// K1: masked pooling partials via bf16 MFMA.
// grid = cB * KCHUNKS (256 wgs), block = 512 (8 waves)
// pooled[b][n][c] += sum_{hw in chunk} vf[b][c][hw] * (mask[b][n][hw] > 0.5)
// msum[b][n]      += popcount of mask bits in chunk
// ---------------------------------------------------------------------------
__global__ __launch_bounds__(512, 1)
void pool_kernel(const float* __restrict__ vf, const float* __restrict__ masks,
                 float* __restrict__ pooled, unsigned* __restrict__ msum)
{
    __shared__ unsigned short Atile[NPAD * KS];  // mask bf16, [n][k], XOR-swizzled
    __shared__ unsigned short Btile[cC * KS];    // vf  bf16, [c][k], XOR-swizzled
    __shared__ unsigned msum_l[NPAD];

    const int tid  = threadIdx.x;
    const int lane = tid & 63;
    const int w    = tid >> 6;              // wave 0..7
    const int b    = blockIdx.x / KCHUNKS;
    const int p0   = (blockIdx.x % KCHUNKS) * KC;

    const int l15 = lane & 15;
    const int lk  = lane >> 4;              // 0..3

    if (tid < NPAD) msum_l[tid] = 0;
    // zero pad rows n=100..111 once (never overwritten afterwards)
    for (int i = tid; i < (NPAD - cN) * KS; i += 512)
        Atile[cN * KS + i] = 0;
    __syncthreads();

    floatx4 acc[7][2];
    #pragma unroll
    for (int mt = 0; mt < 7; ++mt)
        #pragma unroll
        for (int cc = 0; cc < 2; ++cc)
            acc[mt][cc] = (floatx4){0.f, 0.f, 0.f, 0.f};

    for (int s = 0; s < NSUB; ++s) {
        const int px = p0 + s * KS;

        // ---- stage vf tile: 256 c-rows x 128 px, fp32 -> bf16, swizzled LDS
        {
            const float* src = vf + (size_t)b * cC * cHW + px;
            const int q  = tid & 31;        // which float4 along the 128 pixels
            const int c0 = tid >> 5;        // 0..15
            #pragma unroll
            for (int it = 0; it < 16; ++it) {
                const int c = c0 + it * 16;
                const floatx4 v = *(const floatx4*)(src + (size_t)c * cHW + q * 4);
                unsigned lo = (unsigned)f2bf(v.x) | ((unsigned)f2bf(v.y) << 16);
                unsigned hi = (unsigned)f2bf(v.z) | ((unsigned)f2bf(v.w) << 16);
                const int byte = c * 256 + ((q * 8) ^ ((c & 7) << 4));
                *(uint2*)((char*)Btile + byte) = make_uint2(lo, hi);
            }
        }
        // ---- stage mask tile: 100 n-rows x 128 px, binarize -> bf16 0/1
        {
            const float* src = masks + (size_t)b * cN * cHW + px;
            for (int idx = tid; idx < cN * 32; idx += 512) {
                const int n = idx >> 5, q = idx & 31;
                const floatx4 v = *(const floatx4*)(src + (size_t)n * cHW + q * 4);
                const int b0 = v.x > 0.5f, b1 = v.y > 0.5f, b2 = v.z > 0.5f, b3 = v.w > 0.5f;
                unsigned lo = (b0 ? 0x3F80u : 0u) | ((b1 ? 0x3F80u : 0u) << 16);
                unsigned hi = (b2 ? 0x3F80u : 0u) | ((b3 ? 0x3F80u : 0u) << 16);
                const int byte = n * 256 + ((q * 8) ^ ((n & 7) << 4));
                *(uint2*)((char*)Atile + byte) = make_uint2(lo, hi);
                const int cnt = b0 + b1 + b2 + b3;
                if (cnt) atomicAdd(&msum_l[n], (unsigned)cnt);
            }
        }
        __syncthreads();

        // ---- MFMA: D(112x256) += A(112x128) * B(128x256), 4 k-steps of 32
        #pragma unroll
        for (int ks = 0; ks < 4; ++ks) {
            const int kbyte = ks * 64 + lk * 16;   // (k = ks*32 + lk*8) * 2B
            short8 bfr[2];
            #pragma unroll
            for (int cc = 0; cc < 2; ++cc) {
                const int c = (w * 2 + cc) * 16 + l15;
                bfr[cc] = *(const short8*)((const char*)Btile + c * 256 + (kbyte ^ ((c & 7) << 4)));
            }
            #pragma unroll
            for (int mt = 0; mt < 7; ++mt) {
                const int m = mt * 16 + l15;
                const short8 afr = *(const short8*)((const char*)Atile + m * 256 + (kbyte ^ ((m & 7) << 4)));
                #pragma unroll
                for (int cc = 0; cc < 2; ++cc)
                    acc[mt][cc] = __builtin_amdgcn_mfma_f32_16x16x32_bf16(afr, bfr[cc], acc[mt][cc], 0, 0, 0);
            }
        }
        __syncthreads();
    }

    // ---- write partials: C/D layout col=lane&15, row=(lane>>4)*4+i
    #pragma unroll
    for (int mt = 0; mt < 7; ++mt) {
        const int nbase = mt * 16 + lk * 4;
        #pragma unroll
        for (int i = 0; i < 4; ++i) {
            const int n = nbase + i;
            if (n < cN) {
                #pragma unroll
                for (int cc = 0; cc < 2; ++cc) {
                    const int c = (w * 2 + cc) * 16 + l15;
                    atomicAdd(&pooled[((size_t)b * cN + n) * cC + c], acc[mt][cc][i]);
                }
            }
        }
    }
    if (tid < cN) atomicAdd(&msum[b * cN + tid], msum_l[tid]);
}

// ---------------------------------------------------------------------------
// K2: per (b,n) row -> normalize, sims vs 6 normalized text rows, CE, masked sum
// grid = 200 blocks x 256 threads = 800 waves, one wave per row
// ---------------------------------------------------------------------------
__device__ __forceinline__ float wred(float v) {
    #pragma unroll
    for (int off = 32; off > 0; off >>= 1) v += __shfl_xor(v, off, 64);
    return v;
}

__global__ __launch_bounds__(256)
void finalize_kernel(const float* __restrict__ pooled, const unsigned* __restrict__ msum,
                     const float* __restrict__ text, const int* __restrict__ labels,
                     const float* __restrict__ temp, float* __restrict__ sums)
{
    const int lane = threadIdx.x & 63;
    const int row  = blockIdx.x * 4 + (threadIdx.x >> 6);
    if (row >= cB * cN) return;

    const float m   = (float)msum[row];
    const float inv = 1.0f / fmaxf(m, 1.0f);
    floatx4 p = *(const floatx4*)(pooled + (size_t)row * cC + lane * 4);
    p.x *= inv; p.y *= inv; p.z *= inv; p.w *= inv;

    float psq = p.x * p.x + p.y * p.y + p.z * p.z + p.w * p.w;
    float dot[cT], tsq[cT];
    #pragma unroll
    for (int t = 0; t < cT; ++t) {
        const floatx4 x = *(const floatx4*)(text + (size_t)t * cC + lane * 4);
        dot[t] = p.x * x.x + p.y * x.y + p.z * x.z + p.w * x.w;
        tsq[t] = x.x * x.x + x.y * x.y + x.z * x.z + x.w * x.w;
    }
    psq = wred(psq);
    #pragma unroll
    for (int t = 0; t < cT; ++t) { dot[t] = wred(dot[t]); tsq[t] = wred(tsq[t]); }

    if (lane == 0) {
        const float tempv = fabsf(temp[0]);
        const float pn = fmaxf(sqrtf(psq), 1e-12f);
        float sims[cT], mx = -1e30f;
        #pragma unroll
        for (int t = 0; t < cT; ++t) {
            sims[t] = dot[t] / (pn * fmaxf(sqrtf(tsq[t]), 1e-12f)) / tempv;
            mx = fmaxf(mx, sims[t]);
        }
        float se = 0.f;
        #pragma unroll
        for (int t = 0; t < cT; ++t) se += expf(sims[t] - mx);
        const float lse = logf(se);

        const int lab = labels[row];
        const int tgt = min(max(lab - 1, 0), cT - 1);
        const float ce = -(sims[tgt] - mx - lse);
        const bool valid = (lab >= 1) && (lab <= cT) && (m >= 1.0f);
        if (valid) {
            atomicAdd(&sums[0], ce);
            atomicAdd(&sums[1], 1.0f);
        }
    }
}

__global__ void loss_kernel(const float* __restrict__ sums, float* __restrict__ out) {
    const float s = sums[0], c = sums[1];
    out[0] = (c > 0.f) ? s / fmaxf(c, 1.f) : 0.f;
}

// ---------------------------------------------------------------------------
extern "C" void kernel_launch(void* const* d_in, const int* in_sizes, int n_in,
                              void* d_out, int out_size, void* d_ws, size_t ws_size,
                              hipStream_t stream)
{
    const float* vf     = (const float*)d_in[0];
    const float* text   = (const float*)d_in[1];
    const float* masks  = (const float*)d_in[2];
    const int*   labels = (const int*)d_in[3];
    const float* temp   = (const float*)d_in[4];

    float*    wsf    = (float*)d_ws;
    float*    sums   = wsf;                       // [0]=sum(ce*valid), [1]=cnt
    float*    pooled = wsf + 8;                   // cB*cN*cC fp32
    unsigned* msum   = (unsigned*)(wsf + 8 + cB * cN * cC);

    const size_t zero_bytes = (size_t)(8 + cB * cN * cC + cB * cN) * sizeof(float);
    hipMemsetAsync(d_ws, 0, zero_bytes, stream);

    hipLaunchKernelGGL(pool_kernel, dim3(cB * KCHUNKS), dim3(512), 0, stream,
                       vf, masks, pooled, msum);
    hipLaunchKernelGGL(finalize_kernel, dim3((cB * cN + 3) / 4), dim3(256), 0, stream,
                       pooled, msum, text, labels, temp, sums);
    hipLaunchKernelGGL(loss_kernel, dim3(1), dim3(1), 0, stream,
                       sums, (float*)d_out);
}

// Round 2
// 77.470 us; speedup vs baseline: 1.4059x; 1.4059x over previous
//
#include <hip/hip_runtime.h>
#include <hip/hip_bf16.h>
#include <stdint.h>

// Problem constants (from reference setup_inputs)
constexpr int cB  = 8;
constexpr int cC  = 256;
constexpr int cHW = 128 * 128;   // 16384
constexpr int cN  = 100;
constexpr int cT  = 6;
constexpr int NPAD = 112;        // cN padded to multiple of 16
constexpr int CH  = 128;         // channels per block (C split in 2)
constexpr int KC  = 512;         // pixels per workgroup chunk
constexpr int KS  = 128;         // pixels per LDS subtile
constexpr int NSUB = KC / KS;    // 4
constexpr int KCHUNKS = cHW / KC; // 32

typedef __attribute__((ext_vector_type(8))) short short8;
typedef __attribute__((ext_vector_type(4))) float floatx4;

__device__ __forceinline__ unsigned short f2bf(float f) {
    union { float f; unsigned u; } v; v.f = f;
    unsigned u = v.u;
    unsigned r = u + 0x7fffu + ((u >> 16) & 1u);   // RNE
    return (unsigned short)(r >> 16);
}

// ---------------------------------------------------------------------------
// K1: masked pooling partials via bf16 MFMA.
// grid = KCHUNKS * cB * 2 (512 wgs), block = 512 (8 waves), 2 blocks/CU
// bid = k*16 + b*2 + ch; block computes part[bid][n][c_local] =
//   sum_{px in chunk k} mask_bin[b][n][px] * vf[b][ch*128+c_local][px]
// ---------------------------------------------------------------------------
template<bool USE_PART>
__global__ __launch_bounds__(512, 4)
void pool_kernel(const float* __restrict__ vf, const float* __restrict__ masks,
                 float* __restrict__ part, float* __restrict__ pooled,
                 unsigned* __restrict__ msum)
{
    __shared__ unsigned short Atile[NPAD * KS];  // mask bf16 [n][k], swizzled (28.7 KB)
    __shared__ unsigned short Btile[CH * KS];    // vf  bf16 [c][k], swizzled (32.8 KB)

    const int tid  = threadIdx.x;
    const int lane = tid & 63;
    const int w    = tid >> 6;               // wave 0..7
    const int bid  = blockIdx.x;
    const int k    = bid >> 4;               // 0..31
    const int b    = (bid >> 1) & 7;
    const int ch   = bid & 1;
    const int p0   = k * KC;

    const int l15 = lane & 15;
    const int lk  = lane >> 4;               // 0..3

    // zero pad rows n=100..111 once (never overwritten afterwards)
    for (int i = tid; i < (NPAD - cN) * KS; i += 512)
        Atile[cN * KS + i] = 0;

    floatx4 acc[7];
    #pragma unroll
    for (int mt = 0; mt < 7; ++mt) acc[mt] = (floatx4){0.f, 0.f, 0.f, 0.f};

    int cnts[7];
    #pragma unroll
    for (int i = 0; i < 7; ++i) cnts[i] = 0;

    const float* vsrc0 = vf    + ((size_t)b * cC + ch * CH) * cHW + p0;
    const float* msrc0 = masks + (size_t)b * cN * cHW + p0;

    for (int s = 0; s < NSUB; ++s) {
        const int px = s * KS;

        // ---- stage vf tile: 128 c-rows x 128 px, fp32 -> bf16, swizzled LDS
        {
            const float* src = vsrc0 + px;
            const int q  = tid & 31;         // float4 index along 128 px
            const int c0 = tid >> 5;         // 0..15
            #pragma unroll
            for (int it = 0; it < 8; ++it) {
                const int c = it * 16 + c0;
                const floatx4 v = *(const floatx4*)(src + (size_t)c * cHW + q * 4);
                unsigned lo = (unsigned)f2bf(v.x) | ((unsigned)f2bf(v.y) << 16);
                unsigned hi = (unsigned)f2bf(v.z) | ((unsigned)f2bf(v.w) << 16);
                const int byte = c * 256 + ((q * 8) ^ ((c & 7) << 4));
                *(uint2*)((char*)Btile + byte) = make_uint2(lo, hi);
            }
        }
        // ---- stage mask tile: 100 n-rows x 128 px, binarize -> bf16 0/1
        {
            const float* src = msrc0 + px;
            #pragma unroll
            for (int i = 0; i < 7; ++i) {
                const int idx = tid + i * 512;
                if (idx < cN * 32) {
                    const int n = idx >> 5, q = idx & 31;
                    const floatx4 v = *(const floatx4*)(src + (size_t)n * cHW + q * 4);
                    const int b0 = v.x > 0.5f, b1 = v.y > 0.5f, b2 = v.z > 0.5f, b3 = v.w > 0.5f;
                    unsigned lo = (b0 ? 0x3F80u : 0u) | ((b1 ? 0x3F80u : 0u) << 16);
                    unsigned hi = (b2 ? 0x3F80u : 0u) | ((b3 ? 0x3F80u : 0u) << 16);
                    const int byte = n * 256 + ((q * 8) ^ ((n & 7) << 4));
                    *(uint2*)((char*)Atile + byte) = make_uint2(lo, hi);
                    cnts[i] += b0 + b1 + b2 + b3;
                }
            }
        }
        __syncthreads();

        // ---- MFMA: D(112x128) += A(112x128pxK) * B(128pxK x 128c), 4 k-steps
        #pragma unroll
        for (int ks = 0; ks < 4; ++ks) {
            const int kbyte = ks * 64 + lk * 16;   // (k = ks*32 + lk*8) * 2B
            const int c = w * 16 + l15;            // wave owns one 16-wide c-tile
            const short8 bfr = *(const short8*)((const char*)Btile + c * 256 + (kbyte ^ ((c & 7) << 4)));
            #pragma unroll
            for (int mt = 0; mt < 7; ++mt) {
                const int m = mt * 16 + l15;
                const short8 afr = *(const short8*)((const char*)Atile + m * 256 + (kbyte ^ ((m & 7) << 4)));
                acc[mt] = __builtin_amdgcn_mfma_f32_16x16x32_bf16(afr, bfr, acc[mt], 0, 0, 0);
            }
        }
        __syncthreads();
    }

    // ---- write partials: C/D layout col(lane&15)=c-tile idx, row=(lane>>4)*4+i=n
    if (USE_PART) {
        float* dst = part + (size_t)bid * (cN * CH);
        #pragma unroll
        for (int mt = 0; mt < 7; ++mt) {
            #pragma unroll
            for (int i = 0; i < 4; ++i) {
                const int n = mt * 16 + lk * 4 + i;
                if (n < cN) dst[n * CH + w * 16 + l15] = acc[mt][i];
            }
        }
    } else {
        #pragma unroll
        for (int mt = 0; mt < 7; ++mt) {
            #pragma unroll
            for (int i = 0; i < 4; ++i) {
                const int n = mt * 16 + lk * 4 + i;
                if (n < cN)
                    atomicAdd(&pooled[((size_t)b * cN + n) * cC + ch * CH + w * 16 + l15], acc[mt][i]);
            }
        }
    }

    // ---- msum: half-wave shuffle reduce, one atomic per row per block (ch 0 only)
    if (ch == 0) {
        #pragma unroll
        for (int i = 0; i < 7; ++i) {
            const int idx = tid + i * 512;
            if (idx < cN * 32) {
                int r = cnts[i];
                r += __shfl_xor(r, 1);  r += __shfl_xor(r, 2);
                r += __shfl_xor(r, 4);  r += __shfl_xor(r, 8);
                r += __shfl_xor(r, 16);
                if ((lane & 31) == 0)
                    atomicAdd(&msum[b * cN + (idx >> 5)], (unsigned)r);
            }
        }
    }
}

// ---------------------------------------------------------------------------
// K2: reduce partials + per (b,n) row -> normalize, sims, CE, masked sum
// grid = 200 blocks x 256 threads = 800 waves, one wave per row
// ---------------------------------------------------------------------------
__device__ __forceinline__ float wred(float v) {
    #pragma unroll
    for (int off = 32; off > 0; off >>= 1) v += __shfl_xor(v, off, 64);
    return v;
}

template<bool USE_PART>
__global__ __launch_bounds__(256)
void finalize_kernel(const float* __restrict__ pp, const unsigned* __restrict__ msum,
                     const float* __restrict__ text, const int* __restrict__ labels,
                     const float* __restrict__ temp, float* __restrict__ sums)
{
    const int lane = threadIdx.x & 63;
    const int row  = blockIdx.x * 4 + (threadIdx.x >> 6);
    if (row >= cB * cN) return;
    const int b = row / cN, n = row % cN;
    const int ch = lane >> 5;
    const int cb = (lane & 31) * 4;
    const int c_global = ch * CH + cb;

    floatx4 p = (floatx4){0.f, 0.f, 0.f, 0.f};
    if (USE_PART) {
        const float* src = pp + (size_t)(b * 2 + ch) * (cN * CH) + n * CH + cb;
        #pragma unroll
        for (int kk = 0; kk < KCHUNKS; ++kk)
            p += *(const floatx4*)(src + (size_t)kk * 16 * (cN * CH));
    } else {
        p = *(const floatx4*)(pp + (size_t)row * cC + c_global);
    }

    const float m   = (float)msum[row];
    const float inv = 1.0f / fmaxf(m, 1.0f);
    p.x *= inv; p.y *= inv; p.z *= inv; p.w *= inv;

    float psq = p.x * p.x + p.y * p.y + p.z * p.z + p.w * p.w;
    float dot[cT], tsq[cT];
    #pragma unroll
    for (int t = 0; t < cT; ++t) {
        const floatx4 x = *(const floatx4*)(text + (size_t)t * cC + c_global);
        dot[t] = p.x * x.x + p.y * x.y + p.z * x.z + p.w * x.w;
        tsq[t] = x.x * x.x + x.y * x.y + x.z * x.z + x.w * x.w;
    }
    psq = wred(psq);
    #pragma unroll
    for (int t = 0; t < cT; ++t) { dot[t] = wred(dot[t]); tsq[t] = wred(tsq[t]); }

    if (lane == 0) {
        const float tempv = fabsf(temp[0]);
        const float pn = fmaxf(sqrtf(psq), 1e-12f);
        float sims[cT], mx = -1e30f;
        #pragma unroll
        for (int t = 0; t < cT; ++t) {
            sims[t] = dot[t] / (pn * fmaxf(sqrtf(tsq[t]), 1e-12f)) / tempv;
            mx = fmaxf(mx, sims[t]);
        }
        float se = 0.f;
        #pragma unroll
        for (int t = 0; t < cT; ++t) se += expf(sims[t] - mx);
        const float lse = logf(se);

        const int lab = labels[row];
        const int tgt = min(max(lab - 1, 0), cT - 1);
        const float ce = -(sims[tgt] - mx - lse);
        const bool valid = (lab >= 1) && (lab <= cT) && (m >= 1.0f);
        if (valid) {
            atomicAdd(&sums[0], ce);
            atomicAdd(&sums[1], 1.0f);
        }
    }
}

__global__ void loss_kernel(const float* __restrict__ sums, float* __restrict__ out) {
    const float s = sums[0], c = sums[1];
    out[0] = (c > 0.f) ? s / fmaxf(c, 1.f) : 0.f;
}

// ---------------------------------------------------------------------------
extern "C" void kernel_launch(void* const* d_in, const int* in_sizes, int n_in,
                              void* d_out, int out_size, void* d_ws, size_t ws_size,
                              hipStream_t stream)
{
    const float* vf     = (const float*)d_in[0];
    const float* text   = (const float*)d_in[1];
    const float* masks  = (const float*)d_in[2];
    const int*   labels = (const int*)d_in[3];
    const float* temp   = (const float*)d_in[4];

    float*    wsf  = (float*)d_ws;
    float*    sums = wsf;                    // [0]=sum(ce*valid), [1]=cnt
    unsigned* msum = (unsigned*)(wsf + 8);   // 800 u32
    float*    part = wsf + 4096;             // 512 * 100 * 128 fp32 (26.2 MB)
    float*    pooled = wsf + 1024;           // fallback: 800*256 fp32

    const size_t PART_FLOATS = (size_t)KCHUNKS * cB * 2 * cN * CH;
    const bool use_part = ws_size >= (4096 + PART_FLOATS) * sizeof(float);

    if (use_part) {
        hipMemsetAsync(d_ws, 0, 4096 * sizeof(float), stream);  // sums + msum
        hipLaunchKernelGGL((pool_kernel<true>), dim3(KCHUNKS * cB * 2), dim3(512), 0, stream,
                           vf, masks, part, nullptr, msum);
        hipLaunchKernelGGL((finalize_kernel<true>), dim3((cB * cN + 3) / 4), dim3(256), 0, stream,
                           part, msum, text, labels, temp, sums);
    } else {
        hipMemsetAsync(d_ws, 0, (1024 + (size_t)cB * cN * cC) * sizeof(float), stream);
        hipLaunchKernelGGL((pool_kernel<false>), dim3(KCHUNKS * cB * 2), dim3(512), 0, stream,
                           vf, masks, nullptr, pooled, msum);
        hipLaunchKernelGGL((finalize_kernel<false>), dim3((cB * cN + 3) / 4), dim3(256), 0, stream,
                           pooled, msum, text, labels, temp, sums);
    }
    hipLaunchKernelGGL(loss_kernel, dim3(1), dim3(1), 0, stream,
                       sums, (float*)d_out);
}